// Round 11
// baseline (84.091 us; speedup 1.0000x reference)
//
#include <hip/hip_runtime.h>
#include <math.h>

#define NN 50000
#define NE 800000
#define KD 256      // 2*D
#define DD 128
#define NTILE 3125  // 16-row wave-tiles (50000 = 3125*16)
#define GRID 256

// SpMV privatization geometry
#define EC 64
#define NR 4
#define RNG 12500
#define QPC 3125
#define NPB 196     // nodes per block in phase 3 (256*196 >= 50000)

// workspace layout (floats)
#define S_OFF   0
#define P_OFF   50176
#define CNT_OFF (P_OFF + EC * NN)
#define W1P_OFF (CNT_OFF + 16)
#define WS_NEED ((size_t)(W1P_OFF + DD * KD / 2 + 16) * 4)

typedef __bf16 bf16x4 __attribute__((ext_vector_type(4)));
typedef __bf16 bf16x8 __attribute__((ext_vector_type(8)));
typedef float f32x4 __attribute__((ext_vector_type(4)));

// Init: W1 f32 [128][256] -> FRAGMENT-MAJOR bf16 in ws; zero out + sync counters.
// W1p[((dt*8+ks)*64 + g*16+li)*8 + j] = W1[(dt*16+li)*256 + ks*32 + g*8 + j]
__global__ void init_kernel(const float* __restrict__ W1, __bf16* __restrict__ W1p,
                            float* __restrict__ out, unsigned* __restrict__ cnt)
{
    int i = blockIdx.x * 256 + threadIdx.x;
    if (i == 0) { out[0] = 0.f; cnt[0] = 0u; cnt[1] = 0u; cnt[2] = 0u; }
    if (i >= DD * 8 * 4) return;
    int g  = i & 3;
    int ks = (i >> 2) & 7;
    int d  = i >> 5;
    int dt = d >> 4, li = d & 15;
    const float* src = W1 + d * KD + ks * 32 + g * 8;
    float4 v0 = *(const float4*)(src);
    float4 v1 = *(const float4*)(src + 4);
    bf16x8 h = { (__bf16)v0.x, (__bf16)v0.y, (__bf16)v0.z, (__bf16)v0.w,
                 (__bf16)v1.x, (__bf16)v1.y, (__bf16)v1.z, (__bf16)v1.w };
    *(bf16x8*)&W1p[(size_t)(((dt * 8 + ks) * 64) + g * 16 + li) * 8] = h;
}

// The whole pipeline in one persistent kernel. 256 blocks x 1024 threads; 88 KB LDS
// forces 1 block/CU -> all 256 co-resident -> spin-counter grid sync is safe.
__global__ __launch_bounds__(1024, 4) void mega_kernel(
    const float* __restrict__ x, const __bf16* __restrict__ W1p,
    const float* __restrict__ b1, const float* __restrict__ W2,
    const int* __restrict__ erow, const int* __restrict__ ecol,
    const float* __restrict__ ew, const float* __restrict__ b2,
    float* __restrict__ s, float* __restrict__ P,
    float* __restrict__ out, unsigned* __restrict__ cnt)
{
    __shared__ __align__(16) unsigned char smem[90112];  // 88 KB: W1p (64K) / lt (50K) / red
    const int tid = threadIdx.x;
    const int bid = blockIdx.x;

    // ---- Phase 0: stage frag-major W1p (64 KB) into LDS (own-block use only) ----
    {
        float4*       dst = (float4*)smem;
        const float4* src = (const float4*)W1p;
        #pragma unroll
        for (int i = 0; i < 4; ++i) dst[tid + i * 1024] = src[tid + i * 1024];
    }
    __syncthreads();

    // ---- Phase 1: s[m] = sum_d W2[d]*sin((x@W1^T)[m,d]+b1[d]) ----
    // One wave = one 16-row tile x all 128 d. A per-lane direct from global (1x traffic,
    // coalesced); B from LDS (conflict-free b128: lanes consecutive 16B). No barriers.
    {
        const __bf16* w1s = (const __bf16*)smem;
        const int lane = tid & 63, wid = tid >> 6;
        const int g = lane >> 4, li = lane & 15;
        const int tw = bid * 16 + wid;          // 4096 waves >= 3125 tiles
        if (tw < NTILE) {
            const int m0 = tw * 16;
            const float* xrow = x + (size_t)(m0 + li) * KD + g * 8;
            f32x4 acc[8] = {};
            #pragma unroll
            for (int ks = 0; ks < 8; ++ks) {
                float4 al = *(const float4*)(xrow + ks * 32);
                float4 ah = *(const float4*)(xrow + ks * 32 + 4);
                bf16x8 a = { (__bf16)al.x, (__bf16)al.y, (__bf16)al.z, (__bf16)al.w,
                             (__bf16)ah.x, (__bf16)ah.y, (__bf16)ah.z, (__bf16)ah.w };
                #pragma unroll
                for (int dt = 0; dt < 8; ++dt) {
                    bf16x8 bfr = *(const bf16x8*)&w1s[(size_t)((dt * 8 + ks) * 64 + lane) * 8];
                    acc[dt] = __builtin_amdgcn_mfma_f32_16x16x32_bf16(a, bfr, acc[dt], 0, 0, 0);
                }
            }
            float b1v[8], w2v[8];
            #pragma unroll
            for (int dt = 0; dt < 8; ++dt) { b1v[dt] = b1[dt * 16 + li]; w2v[dt] = W2[dt * 16 + li]; }
            // C/D layout: col(d)=li, row(m)=g*4+r
            #pragma unroll
            for (int r = 0; r < 4; ++r) {
                float v = 0.f;
                #pragma unroll
                for (int dt = 0; dt < 8; ++dt)
                    v += __sinf(acc[dt][r] + b1v[dt]) * w2v[dt];
                v += __shfl_xor(v, 1); v += __shfl_xor(v, 2);
                v += __shfl_xor(v, 4); v += __shfl_xor(v, 8);
                if (li == 0) s[m0 + g * 4 + r] = v;
            }
        }
    }

    // ---- Grid sync 1 (release s; acquire for readers) ----
    __syncthreads();
    if (tid == 0) {
        __threadfence();                        // flush s to device coherence point
        atomicAdd(&cnt[0], 1u);
        while (atomicAdd(&cnt[0], 0u) < GRID) __builtin_amdgcn_s_sleep(2);
        __threadfence();                        // invalidate local caches -> fresh s
    }
    __syncthreads();

    // ---- Phase 2: privatized SpMV. block (nr,ecid): scan chunk, LDS-accumulate range ----
    {
        float* lt = (float*)smem;
        const int ecid = bid & 63;
        const int nr   = bid >> 6;
        const int base = nr * RNG;

        for (int i = tid; i < RNG; i += 1024) lt[i] = 0.f;
        __syncthreads();

        const int4*   r4p = (const int4*)erow;
        const int4*   c4p = (const int4*)ecol;
        const float4* w4p = (const float4*)ew;
        for (int q = tid; q < QPC; q += 1024) {
            int i = ecid * QPC + q;
            int4   r4 = r4p[i];
            int4   c4 = c4p[i];
            float4 w4 = w4p[i];
            unsigned a;
            a = (unsigned)(r4.x - base); if (a < RNG) atomicAdd(&lt[a], w4.x * s[c4.x]);
            a = (unsigned)(r4.y - base); if (a < RNG) atomicAdd(&lt[a], w4.y * s[c4.y]);
            a = (unsigned)(r4.z - base); if (a < RNG) atomicAdd(&lt[a], w4.z * s[c4.z]);
            a = (unsigned)(r4.w - base); if (a < RNG) atomicAdd(&lt[a], w4.w * s[c4.w]);
        }
        __syncthreads();

        float4*       dst = (float4*)(P + (size_t)ecid * NN + base);
        const float4* src = (const float4*)lt;
        for (int j = tid; j < RNG / 4; j += 1024) dst[j] = src[j];
    }

    // ---- Grid sync 2 (release P; acquire for readers) ----
    __syncthreads();
    if (tid == 0) {
        __threadfence();
        atomicAdd(&cnt[1], 1u);
        while (atomicAdd(&cnt[1], 0u) < GRID) __builtin_amdgcn_s_sleep(2);
        __threadfence();
    }
    __syncthreads();

    // ---- Phase 3: out += sum_n sin(sum_ec P[ec][n] + b2)^2 ; last block sqrt ----
    {
        float v = 0.f;
        int n = bid * NPB + tid;
        if (tid < NPB && n < NN) {
            float a = 0.f;
            #pragma unroll 8
            for (int ec = 0; ec < EC; ++ec) a += P[(size_t)ec * NN + n];
            float o = __sinf(a + b2[0]);
            v = o * o;
        }
        #pragma unroll
        for (int off = 32; off; off >>= 1) v += __shfl_xor(v, off);
        float* red = (float*)smem;              // safe: phase-2 smem reads done (sync 2)
        if ((tid & 63) == 0) red[tid >> 6] = v;
        __syncthreads();
        if (tid == 0) {
            float tot = 0.f;
            #pragma unroll
            for (int i = 0; i < 16; ++i) tot += red[i];
            atomicAdd(out, tot);
            __threadfence();
            unsigned old = atomicAdd(&cnt[2], 1u);
            if (old == GRID - 1)
                out[0] = sqrtf(atomicAdd(out, 0.f));  // all adds visible via atomic chain
        }
    }
}

// ---- Fallback path (small workspace): validated R9/R10 separate-kernel chain ----
__global__ __launch_bounds__(256, 4) void stage1_fb_kernel(
    const float* __restrict__ x, const __bf16* __restrict__ W1p,
    const float* __restrict__ b1, const float* __restrict__ W2,
    float* __restrict__ s)
{
    const int tid  = threadIdx.x;
    const int lane = tid & 63;
    const int w    = tid >> 6;
    const int g    = lane >> 4;
    const int li   = lane & 15;
    const int tw   = blockIdx.x * 4 + w;
    if (tw >= NTILE) return;
    const int m0   = tw * 16;
    const float* xrow = x + (size_t)(m0 + li) * KD + g * 8;
    float b1v[8], w2v[8];
    #pragma unroll
    for (int dt = 0; dt < 8; ++dt) { b1v[dt] = b1[dt * 16 + li]; w2v[dt] = W2[dt * 16 + li]; }
    const __bf16* fbase = W1p + (size_t)lane * 8;
    f32x4 acc[8] = {};
    #pragma unroll
    for (int ks = 0; ks < 8; ++ks) {
        float4 al = *(const float4*)(xrow + ks * 32);
        float4 ah = *(const float4*)(xrow + ks * 32 + 4);
        bf16x8 a = { (__bf16)al.x, (__bf16)al.y, (__bf16)al.z, (__bf16)al.w,
                     (__bf16)ah.x, (__bf16)ah.y, (__bf16)ah.z, (__bf16)ah.w };
        #pragma unroll
        for (int dt = 0; dt < 8; ++dt) {
            bf16x8 bfr = *(const bf16x8*)(fbase + (size_t)((dt * 8 + ks) * 64) * 8);
            acc[dt] = __builtin_amdgcn_mfma_f32_16x16x32_bf16(a, bfr, acc[dt], 0, 0, 0);
        }
    }
    #pragma unroll
    for (int r = 0; r < 4; ++r) {
        float v = 0.f;
        #pragma unroll
        for (int dt = 0; dt < 8; ++dt) v += __sinf(acc[dt][r] + b1v[dt]) * w2v[dt];
        v += __shfl_xor(v, 1); v += __shfl_xor(v, 2);
        v += __shfl_xor(v, 4); v += __shfl_xor(v, 8);
        if (li == 0) s[m0 + g * 4 + r] = v;
    }
}

__global__ void spmv_fb_kernel(const int* __restrict__ erow, const int* __restrict__ ecol,
                               const float* __restrict__ ew, const float* __restrict__ s,
                               float* __restrict__ t)
{
    int i = blockIdx.x * 256 + threadIdx.x;
    if (i >= NE / 4) return;
    int4   r4 = ((const int4*)erow)[i];
    int4   c4 = ((const int4*)ecol)[i];
    float4 w4 = ((const float4*)ew)[i];
    atomicAdd(&t[r4.x], w4.x * s[c4.x]);
    atomicAdd(&t[r4.y], w4.y * s[c4.y]);
    atomicAdd(&t[r4.z], w4.z * s[c4.z]);
    atomicAdd(&t[r4.w], w4.w * s[c4.w]);
}

__global__ void finish_fb_kernel(const float* __restrict__ t, const float* __restrict__ b2,
                                 float* __restrict__ out)
{
    int n = blockIdx.x * 256 + threadIdx.x;
    float v = 0.f;
    if (n < NN) { float o = __sinf(t[n] + b2[0]); v = o * o; }
    #pragma unroll
    for (int off = 32; off; off >>= 1) v += __shfl_xor(v, off);
    __shared__ float partial[4];
    if ((threadIdx.x & 63) == 0) partial[threadIdx.x >> 6] = v;
    __syncthreads();
    if (threadIdx.x == 0)
        atomicAdd(out, partial[0] + partial[1] + partial[2] + partial[3]);
}

__global__ void sqrt_kernel(float* out) { out[0] = sqrtf(out[0]); }

__global__ void zero_kernel(float* t, float* out)
{
    int i = blockIdx.x * 256 + threadIdx.x;
    if (i < NN) t[i] = 0.f;
    if (i == 0) out[0] = 0.f;
}

extern "C" void kernel_launch(void* const* d_in, const int* in_sizes, int n_in,
                              void* d_out, int out_size, void* d_ws, size_t ws_size,
                              hipStream_t stream)
{
    const float* x   = (const float*)d_in[0];
    const float* W1  = (const float*)d_in[1];
    const float* b1  = (const float*)d_in[2];
    const float* W2  = (const float*)d_in[3];
    const float* b2  = (const float*)d_in[4];
    const int*   er  = (const int*)d_in[5];
    const int*   ec  = ((const int*)d_in[5]) + NE;
    const float* ew  = (const float*)d_in[6];
    float* out = (float*)d_out;

    float*    ws    = (float*)d_ws;
    float*    s_buf = ws + S_OFF;
    float*    P     = ws + P_OFF;
    unsigned* cnt   = (unsigned*)(ws + CNT_OFF);
    __bf16*   W1p   = (__bf16*)(ws + W1P_OFF);

    if (ws_size >= WS_NEED) {
        init_kernel<<<16, 256, 0, stream>>>(W1, W1p, out, cnt);
        mega_kernel<<<GRID, 1024, 0, stream>>>(x, W1p, b1, W2, er, ec, ew, b2,
                                               s_buf, P, out, cnt);
    } else {
        // Dense-atomic fallback (needs ~700 KB of ws)
        float*    t    = ws + P_OFF;
        __bf16*   W1pf = (__bf16*)(ws + P_OFF + NN);
        init_kernel<<<16, 256, 0, stream>>>(W1, W1pf, out,
                                            (unsigned*)(ws + P_OFF + NN + DD * KD / 2));
        zero_kernel<<<(NN + 255) / 256, 256, 0, stream>>>(t, out);
        stage1_fb_kernel<<<(NTILE + 3) / 4, 256, 0, stream>>>(x, W1pf, b1, W2, s_buf);
        spmv_fb_kernel<<<(NE / 4 + 255) / 256, 256, 0, stream>>>(er, ec, ew, s_buf, t);
        finish_fb_kernel<<<(NN + 255) / 256, 256, 0, stream>>>(t, b2, out);
        sqrt_kernel<<<1, 1, 0, stream>>>(out);
    }
}

// Round 13
// 46.750 us; speedup vs baseline: 1.7987x; 1.7987x over previous
//
#include <hip/hip_runtime.h>
#include <math.h>

#define NN 50000
#define NE 800000
#define KD 256      // 2*D
#define DD 128
#define ROWS 32
#define STR 264     // padded LDS row stride (bf16 elems)
#define NT ((NN + ROWS - 1) / ROWS)   // 1563

// SpMV privatization geometry
#define EC 64
#define NR 4
#define RNG 12500
#define QPC 3125

// workspace layout (floats)
#define S_OFF   0
#define P_OFF   50176
#define CNT_OFF (P_OFF + EC * NN)
#define W1P_OFF (CNT_OFF + 16)
#define WS_NEED ((size_t)(W1P_OFF + DD * KD / 2 + 16) * 4)

typedef __bf16 bf16x4 __attribute__((ext_vector_type(4)));
typedef __bf16 bf16x8 __attribute__((ext_vector_type(8)));
typedef float f32x4 __attribute__((ext_vector_type(4)));   // clang ext-vector: OK for nontemporal builtins

// Prep: W1 f32 [128][256] -> FRAGMENT-MAJOR bf16; also zero out/counter.
// W1p[((dt*8+ks)*64 + g*16+li)*8 + j] = W1[(dt*16+li)*256 + ks*32 + g*8 + j]
__global__ void prep_w1_kernel(const float* __restrict__ W1, __bf16* __restrict__ W1p,
                               float* __restrict__ out, unsigned* __restrict__ counter)
{
    int i = blockIdx.x * 256 + threadIdx.x;   // one per (d, ks, g): 128*8*4 = 4096
    if (i == 0) { out[0] = 0.f; counter[0] = 0u; }
    if (i >= DD * 8 * 4) return;
    int g  = i & 3;
    int ks = (i >> 2) & 7;
    int d  = i >> 5;
    int dt = d >> 4, li = d & 15;
    const float* src = W1 + d * KD + ks * 32 + g * 8;
    float4 v0 = *(const float4*)(src);
    float4 v1 = *(const float4*)(src + 4);
    bf16x8 h = { (__bf16)v0.x, (__bf16)v0.y, (__bf16)v0.z, (__bf16)v0.w,
                 (__bf16)v1.x, (__bf16)v1.y, (__bf16)v1.z, (__bf16)v1.w };
    *(bf16x8*)&W1p[(size_t)(((dt * 8 + ks) * 64) + g * 16 + li) * 8] = h;
}

// Stage 1 (MFMA, 4 blocks/CU): one 32-row tile per block; x tile in LDS;
// B-frags streamed from frag-major W1p (L2-hot, coalesced) with 1-step prefetch.
// SINGLE CHANGE vs R6: x staging loads are NONTEMPORAL (L1-bypass) — x has zero
// reuse, and the hypothesis is the per-CU L1 miss path caps x delivery (~1 TB/s).
__global__ __launch_bounds__(256, 4) void stage1_kernel(
    const float* __restrict__ x, const __bf16* __restrict__ W1p,
    const float* __restrict__ b1, const float* __restrict__ W2,
    float* __restrict__ s, float* __restrict__ out, unsigned* __restrict__ counter)
{
    __shared__ __align__(16) __bf16 xs[ROWS * STR];   // 16896 B
    __shared__ float sred[4][ROWS];

    const int tid  = threadIdx.x;
    const int lane = tid & 63;
    const int w    = tid >> 6;
    const int g    = lane >> 4;
    const int li   = lane & 15;
    const int m0   = blockIdx.x * ROWS;

    if (blockIdx.x == 0 && tid == 0) { out[0] = 0.f; counter[0] = 0u; }

    // Issue x tile loads (coalesced 16B, NT/L1-bypass; clamp rows for tail tile)
    f32x4 xr[8];
    const f32x4* xv = (const f32x4*)x;
    #pragma unroll
    for (int i = 0; i < 8; ++i) {
        int c = tid + i * 256;
        int r = c >> 6, kq = c & 63;
        int rr = m0 + r; rr = rr < NN ? rr : NN - 1;
        xr[i] = __builtin_nontemporal_load(xv + (size_t)rr * 64 + kq);
    }

    // Frag-major B bases: wave w owns d-tiles 2w, 2w+1. Prefetch ks=0.
    const __bf16* fb0 = W1p + ((size_t)((2 * w)     * 8) * 64 + lane) * 8;
    const __bf16* fb1 = W1p + ((size_t)((2 * w + 1) * 8) * 64 + lane) * 8;
    bf16x8 nb0 = *(const bf16x8*)(fb0);
    bf16x8 nb1 = *(const bf16x8*)(fb1);

    const int d0 = w * 32 + li;
    const float b1v0 = b1[d0], b1v1 = b1[d0 + 16];
    const float w2v0 = W2[d0], w2v1 = W2[d0 + 16];

    // Convert + stage x tile to LDS
    #pragma unroll
    for (int i = 0; i < 8; ++i) {
        int c = tid + i * 256;
        int r = c >> 6, kq = c & 63;
        bf16x4 h = { (__bf16)xr[i][0], (__bf16)xr[i][1], (__bf16)xr[i][2], (__bf16)xr[i][3] };
        *(bf16x4*)&xs[r * STR + kq * 4] = h;
    }
    __syncthreads();

    // K-loop: A from LDS, B streamed (prefetch ks+1 under ks's MFMAs).
    // k = ks*32 + g*8 + j for lane (g,li) on BOTH sides (same bijection).
    f32x4 acc[2][2] = {};
    #pragma unroll
    for (int ks = 0; ks < 8; ++ks) {
        bf16x8 cb0 = nb0, cb1 = nb1;
        if (ks < 7) {
            nb0 = *(const bf16x8*)(fb0 + (size_t)(ks + 1) * 512);
            nb1 = *(const bf16x8*)(fb1 + (size_t)(ks + 1) * 512);
        }
        const int ko = ks * 32 + g * 8;
        bf16x8 a0 = *(const bf16x8*)&xs[li * STR + ko];
        bf16x8 a1 = *(const bf16x8*)&xs[(li + 16) * STR + ko];
        acc[0][0] = __builtin_amdgcn_mfma_f32_16x16x32_bf16(a0, cb0, acc[0][0], 0, 0, 0);
        acc[0][1] = __builtin_amdgcn_mfma_f32_16x16x32_bf16(a0, cb1, acc[0][1], 0, 0, 0);
        acc[1][0] = __builtin_amdgcn_mfma_f32_16x16x32_bf16(a1, cb0, acc[1][0], 0, 0, 0);
        acc[1][1] = __builtin_amdgcn_mfma_f32_16x16x32_bf16(a1, cb1, acc[1][1], 0, 0, 0);
    }

    // Epilogue: v = sin(acc+b1)*W2, reduce over d (C/D: col=lane&15, row=(lane>>4)*4+reg)
    #pragma unroll
    for (int mt = 0; mt < 2; ++mt) {
        #pragma unroll
        for (int r = 0; r < 4; ++r) {
            float v = __sinf(acc[mt][0][r] + b1v0) * w2v0
                    + __sinf(acc[mt][1][r] + b1v1) * w2v1;
            v += __shfl_xor(v, 1); v += __shfl_xor(v, 2);
            v += __shfl_xor(v, 4); v += __shfl_xor(v, 8);
            if (li == 0) sred[w][mt * 16 + g * 4 + r] = v;
        }
    }
    __syncthreads();
    if (tid < ROWS) {
        int m = m0 + tid;
        if (m < NN) s[m] = sred[0][tid] + sred[1][tid] + sred[2][tid] + sred[3][tid];
    }
}

// Stage 2 (LDS-privatized): block (nr, ecid) scans chunk ecid, accumulates its node
// range in LDS, writes partial range to P[ecid][...]. No device-scope atomics.
__global__ __launch_bounds__(1024, 1) void spmv_lds_kernel(
    const int* __restrict__ erow, const int* __restrict__ ecol,
    const float* __restrict__ ew, const float* __restrict__ s,
    float* __restrict__ P)
{
    __shared__ float lt[RNG];
    const int tid  = threadIdx.x;
    const int ecid = blockIdx.x & 63;
    const int nr   = blockIdx.x >> 6;
    const int base = nr * RNG;

    for (int i = tid; i < RNG; i += 1024) lt[i] = 0.f;
    __syncthreads();

    const int4*   r4p = (const int4*)erow;
    const int4*   c4p = (const int4*)ecol;
    const float4* w4p = (const float4*)ew;
    for (int q = tid; q < QPC; q += 1024) {
        int i = ecid * QPC + q;
        int4   r4 = r4p[i];
        int4   c4 = c4p[i];
        float4 w4 = w4p[i];
        unsigned a;
        a = (unsigned)(r4.x - base); if (a < RNG) atomicAdd(&lt[a], w4.x * s[c4.x]);
        a = (unsigned)(r4.y - base); if (a < RNG) atomicAdd(&lt[a], w4.y * s[c4.y]);
        a = (unsigned)(r4.z - base); if (a < RNG) atomicAdd(&lt[a], w4.z * s[c4.z]);
        a = (unsigned)(r4.w - base); if (a < RNG) atomicAdd(&lt[a], w4.w * s[c4.w]);
    }
    __syncthreads();

    float4*       dst = (float4*)(P + (size_t)ecid * NN + base);
    const float4* src = (const float4*)lt;
    for (int j = tid; j < RNG / 4; j += 1024) dst[j] = src[j];
}

// Stage 3: out += sum_n sin(sum_ec P[ec][n] + b2)^2 ; last block applies sqrt.
__global__ void finish_lds_kernel(const float* __restrict__ P, const float* __restrict__ b2,
                                  float* __restrict__ out, unsigned* __restrict__ counter,
                                  int nblocks)
{
    int n = blockIdx.x * 256 + threadIdx.x;
    float v = 0.f;
    if (n < NN) {
        float a = 0.f;
        #pragma unroll 8
        for (int ec = 0; ec < EC; ++ec) a += P[(size_t)ec * NN + n];
        float o = __sinf(a + b2[0]);
        v = o * o;
    }
    #pragma unroll
    for (int off = 32; off; off >>= 1) v += __shfl_xor(v, off);
    __shared__ float partial[4];
    if ((threadIdx.x & 63) == 0) partial[threadIdx.x >> 6] = v;
    __syncthreads();
    if (threadIdx.x == 0) {
        atomicAdd(out, partial[0] + partial[1] + partial[2] + partial[3]);
        __threadfence();
        unsigned old = atomicAdd(counter, 1u);
        if (old == (unsigned)(nblocks - 1)) {
            float tot = atomicAdd(out, 0.f);   // atomic read: all prior adds visible
            out[0] = sqrtf(tot);
        }
    }
}

// ---- Fallback path (small workspace): dense atomic SpMV ----
__global__ void spmv_fallback_kernel(const int* __restrict__ erow, const int* __restrict__ ecol,
                                     const float* __restrict__ ew, const float* __restrict__ s,
                                     float* __restrict__ t)
{
    int i = blockIdx.x * 256 + threadIdx.x;
    if (i >= NE / 4) return;
    int4   r4 = ((const int4*)erow)[i];
    int4   c4 = ((const int4*)ecol)[i];
    float4 w4 = ((const float4*)ew)[i];
    atomicAdd(&t[r4.x], w4.x * s[c4.x]);
    atomicAdd(&t[r4.y], w4.y * s[c4.y]);
    atomicAdd(&t[r4.z], w4.z * s[c4.z]);
    atomicAdd(&t[r4.w], w4.w * s[c4.w]);
}

__global__ void finish_fallback_kernel(const float* __restrict__ t, const float* __restrict__ b2,
                                       float* __restrict__ out)
{
    int n = blockIdx.x * 256 + threadIdx.x;
    float v = 0.f;
    if (n < NN) { float o = __sinf(t[n] + b2[0]); v = o * o; }
    #pragma unroll
    for (int off = 32; off; off >>= 1) v += __shfl_xor(v, off);
    __shared__ float partial[4];
    if ((threadIdx.x & 63) == 0) partial[threadIdx.x >> 6] = v;
    __syncthreads();
    if (threadIdx.x == 0)
        atomicAdd(out, partial[0] + partial[1] + partial[2] + partial[3]);
}

__global__ void sqrt_kernel(float* out) { out[0] = sqrtf(out[0]); }

__global__ void zero_kernel(float* t, float* out)
{
    int i = blockIdx.x * 256 + threadIdx.x;
    if (i < NN) t[i] = 0.f;
    if (i == 0) out[0] = 0.f;
}

extern "C" void kernel_launch(void* const* d_in, const int* in_sizes, int n_in,
                              void* d_out, int out_size, void* d_ws, size_t ws_size,
                              hipStream_t stream)
{
    const float* x   = (const float*)d_in[0];
    const float* W1  = (const float*)d_in[1];
    const float* b1  = (const float*)d_in[2];
    const float* W2  = (const float*)d_in[3];
    const float* b2  = (const float*)d_in[4];
    const int*   er  = (const int*)d_in[5];
    const int*   ec  = ((const int*)d_in[5]) + NE;
    const float* ew  = (const float*)d_in[6];
    float* out = (float*)d_out;

    float*    ws    = (float*)d_ws;
    float*    s_buf = ws + S_OFF;
    float*    P     = ws + P_OFF;
    unsigned* cnt   = (unsigned*)(ws + CNT_OFF);
    __bf16*   W1p   = (__bf16*)(ws + W1P_OFF);

    if (ws_size >= WS_NEED) {
        prep_w1_kernel<<<16, 256, 0, stream>>>(W1, W1p, out, cnt);
        stage1_kernel<<<NT, 256, 0, stream>>>(x, W1p, b1, W2, s_buf, out, cnt);
        spmv_lds_kernel<<<NR * EC, 1024, 0, stream>>>(er, ec, ew, s_buf, P);
        int fb = (NN + 255) / 256;
        finish_lds_kernel<<<fb, 256, 0, stream>>>(P, b2, out, cnt, fb);
    } else {
        // Dense-atomic fallback (needs ~700 KB of ws)
        __bf16*   W1pf = (__bf16*)(ws + 50176 + NN);
        unsigned* cntf = (unsigned*)(ws + 50176 + NN + DD * KD / 2);
        prep_w1_kernel<<<16, 256, 0, stream>>>(W1, W1pf, out, cntf);
        zero_kernel<<<(NN + 255) / 256, 256, 0, stream>>>(ws + 50176, out);
        stage1_kernel<<<NT, 256, 0, stream>>>(x, W1pf, b1, W2, s_buf, out, cntf);
        spmv_fallback_kernel<<<(NE / 4 + 255) / 256, 256, 0, stream>>>(er, ec, ew, s_buf, ws + 50176);
        finish_fallback_kernel<<<(NN + 255) / 256, 256, 0, stream>>>(ws + 50176, b2, out);
        sqrt_kernel<<<1, 1, 0, stream>>>(out);
    }
}

// Round 14
// 41.319 us; speedup vs baseline: 2.0352x; 1.1314x over previous
//
#include <hip/hip_runtime.h>
#include <math.h>

#define NN 50000
#define NE 800000
#define KD 256      // 2*D
#define DD 128
#define ROWS 32
#define STR 264     // padded LDS row stride (bf16 elems)
#define NT ((NN + ROWS - 1) / ROWS)   // 1563

// SpMV privatization geometry
#define EC 64
#define NR 4
#define RNG 12500
#define QPC 3125

// workspace layout (floats)
#define S_OFF   0
#define P_OFF   50176
#define CNT_OFF (P_OFF + EC * NN)
#define W1P_OFF (CNT_OFF + 16)
#define WS_NEED ((size_t)(W1P_OFF + DD * KD / 2 + 16) * 4)

typedef __bf16 bf16x4 __attribute__((ext_vector_type(4)));
typedef __bf16 bf16x8 __attribute__((ext_vector_type(8)));
typedef float f32x4 __attribute__((ext_vector_type(4)));

// Prep: W1 f32 [128][256] -> FRAGMENT-MAJOR bf16; also zero out/counter.
// W1p[((dt*8+ks)*64 + g*16+li)*8 + j] = W1[(dt*16+li)*256 + ks*32 + g*8 + j]
__global__ void prep_w1_kernel(const float* __restrict__ W1, __bf16* __restrict__ W1p,
                               float* __restrict__ out, unsigned* __restrict__ counter)
{
    int i = blockIdx.x * 256 + threadIdx.x;   // one per (d, ks, g): 128*8*4 = 4096
    if (i == 0) { out[0] = 0.f; counter[0] = 0u; }
    if (i >= DD * 8 * 4) return;
    int g  = i & 3;
    int ks = (i >> 2) & 7;
    int d  = i >> 5;
    int dt = d >> 4, li = d & 15;
    const float* src = W1 + d * KD + ks * 32 + g * 8;
    float4 v0 = *(const float4*)(src);
    float4 v1 = *(const float4*)(src + 4);
    bf16x8 h = { (__bf16)v0.x, (__bf16)v0.y, (__bf16)v0.z, (__bf16)v0.w,
                 (__bf16)v1.x, (__bf16)v1.y, (__bf16)v1.z, (__bf16)v1.w };
    *(bf16x8*)&W1p[(size_t)(((dt * 8 + ks) * 64) + g * 16 + li) * 8] = h;
}

// Stage 1 (MFMA): one 32-row tile per block; x tile in LDS; B-frags streamed from
// frag-major W1p (L2-hot, coalesced) with 1-step prefetch.
// vs R6 (best, 41.36): __launch_bounds__(256,6) for 6 blocks/CU (24 waves), with
// staging split into 2 batches of 4 loads to halve live staging regs (fit <=85 VGPR).
__global__ __launch_bounds__(256, 6) void stage1_kernel(
    const float* __restrict__ x, const __bf16* __restrict__ W1p,
    const float* __restrict__ b1, const float* __restrict__ W2,
    float* __restrict__ s, float* __restrict__ out, unsigned* __restrict__ counter)
{
    __shared__ __align__(16) __bf16 xs[ROWS * STR];   // 16896 B
    __shared__ float sred[4][ROWS];

    const int tid  = threadIdx.x;
    const int lane = tid & 63;
    const int w    = tid >> 6;
    const int g    = lane >> 4;
    const int li   = lane & 15;
    const int m0   = blockIdx.x * ROWS;

    if (blockIdx.x == 0 && tid == 0) { out[0] = 0.f; counter[0] = 0u; }

    const f32x4* xv = (const f32x4*)x;

    // Stage x tile in 2 batches of 4 loads (16 live staging VGPRs instead of 32)
    #pragma unroll
    for (int b = 0; b < 2; ++b) {
        f32x4 xr[4];
        #pragma unroll
        for (int i = 0; i < 4; ++i) {
            int c = tid + (b * 4 + i) * 256;
            int r = c >> 6, kq = c & 63;
            int rr = m0 + r; rr = rr < NN ? rr : NN - 1;
            xr[i] = xv[(size_t)rr * 64 + kq];
        }
        #pragma unroll
        for (int i = 0; i < 4; ++i) {
            int c = tid + (b * 4 + i) * 256;
            int r = c >> 6, kq = c & 63;
            bf16x4 h = { (__bf16)xr[i][0], (__bf16)xr[i][1], (__bf16)xr[i][2], (__bf16)xr[i][3] };
            *(bf16x4*)&xs[r * STR + kq * 4] = h;
        }
    }

    // Frag-major B bases: wave w owns d-tiles 2w, 2w+1. Prefetch ks=0.
    const __bf16* fb0 = W1p + ((size_t)((2 * w)     * 8) * 64 + lane) * 8;
    const __bf16* fb1 = W1p + ((size_t)((2 * w + 1) * 8) * 64 + lane) * 8;
    bf16x8 nb0 = *(const bf16x8*)(fb0);
    bf16x8 nb1 = *(const bf16x8*)(fb1);

    const int d0 = w * 32 + li;
    const float b1v0 = b1[d0], b1v1 = b1[d0 + 16];
    const float w2v0 = W2[d0], w2v1 = W2[d0 + 16];

    __syncthreads();

    // K-loop: A from LDS, B streamed (prefetch ks+1 under ks's MFMAs).
    // k = ks*32 + g*8 + j for lane (g,li) on BOTH sides (same bijection).
    f32x4 acc[2][2] = {};
    #pragma unroll
    for (int ks = 0; ks < 8; ++ks) {
        bf16x8 cb0 = nb0, cb1 = nb1;
        if (ks < 7) {
            nb0 = *(const bf16x8*)(fb0 + (size_t)(ks + 1) * 512);
            nb1 = *(const bf16x8*)(fb1 + (size_t)(ks + 1) * 512);
        }
        const int ko = ks * 32 + g * 8;
        bf16x8 a0 = *(const bf16x8*)&xs[li * STR + ko];
        bf16x8 a1 = *(const bf16x8*)&xs[(li + 16) * STR + ko];
        acc[0][0] = __builtin_amdgcn_mfma_f32_16x16x32_bf16(a0, cb0, acc[0][0], 0, 0, 0);
        acc[0][1] = __builtin_amdgcn_mfma_f32_16x16x32_bf16(a0, cb1, acc[0][1], 0, 0, 0);
        acc[1][0] = __builtin_amdgcn_mfma_f32_16x16x32_bf16(a1, cb0, acc[1][0], 0, 0, 0);
        acc[1][1] = __builtin_amdgcn_mfma_f32_16x16x32_bf16(a1, cb1, acc[1][1], 0, 0, 0);
    }

    // Epilogue: v = sin(acc+b1)*W2, reduce over d (C/D: col=lane&15, row=(lane>>4)*4+reg)
    #pragma unroll
    for (int mt = 0; mt < 2; ++mt) {
        #pragma unroll
        for (int r = 0; r < 4; ++r) {
            float v = __sinf(acc[mt][0][r] + b1v0) * w2v0
                    + __sinf(acc[mt][1][r] + b1v1) * w2v1;
            v += __shfl_xor(v, 1); v += __shfl_xor(v, 2);
            v += __shfl_xor(v, 4); v += __shfl_xor(v, 8);
            if (li == 0) sred[w][mt * 16 + g * 4 + r] = v;
        }
    }
    __syncthreads();
    if (tid < ROWS) {
        int m = m0 + tid;
        if (m < NN) s[m] = sred[0][tid] + sred[1][tid] + sred[2][tid] + sred[3][tid];
    }
}

// Stage 2 (LDS-privatized): block (nr, ecid) scans chunk ecid, accumulates its node
// range in LDS, writes partial range to P[ecid][...]. No device-scope atomics.
__global__ __launch_bounds__(1024, 1) void spmv_lds_kernel(
    const int* __restrict__ erow, const int* __restrict__ ecol,
    const float* __restrict__ ew, const float* __restrict__ s,
    float* __restrict__ P)
{
    __shared__ float lt[RNG];
    const int tid  = threadIdx.x;
    const int ecid = blockIdx.x & 63;
    const int nr   = blockIdx.x >> 6;
    const int base = nr * RNG;

    for (int i = tid; i < RNG; i += 1024) lt[i] = 0.f;
    __syncthreads();

    const int4*   r4p = (const int4*)erow;
    const int4*   c4p = (const int4*)ecol;
    const float4* w4p = (const float4*)ew;
    for (int q = tid; q < QPC; q += 1024) {
        int i = ecid * QPC + q;
        int4   r4 = r4p[i];
        int4   c4 = c4p[i];
        float4 w4 = w4p[i];
        unsigned a;
        a = (unsigned)(r4.x - base); if (a < RNG) atomicAdd(&lt[a], w4.x * s[c4.x]);
        a = (unsigned)(r4.y - base); if (a < RNG) atomicAdd(&lt[a], w4.y * s[c4.y]);
        a = (unsigned)(r4.z - base); if (a < RNG) atomicAdd(&lt[a], w4.z * s[c4.z]);
        a = (unsigned)(r4.w - base); if (a < RNG) atomicAdd(&lt[a], w4.w * s[c4.w]);
    }
    __syncthreads();

    float4*       dst = (float4*)(P + (size_t)ecid * NN + base);
    const float4* src = (const float4*)lt;
    for (int j = tid; j < RNG / 4; j += 1024) dst[j] = src[j];
}

// Stage 3: out += sum_n sin(sum_ec P[ec][n] + b2)^2 ; last block applies sqrt.
__global__ void finish_lds_kernel(const float* __restrict__ P, const float* __restrict__ b2,
                                  float* __restrict__ out, unsigned* __restrict__ counter,
                                  int nblocks)
{
    int n = blockIdx.x * 256 + threadIdx.x;
    float v = 0.f;
    if (n < NN) {
        float a = 0.f;
        #pragma unroll 8
        for (int ec = 0; ec < EC; ++ec) a += P[(size_t)ec * NN + n];
        float o = __sinf(a + b2[0]);
        v = o * o;
    }
    #pragma unroll
    for (int off = 32; off; off >>= 1) v += __shfl_xor(v, off);
    __shared__ float partial[4];
    if ((threadIdx.x & 63) == 0) partial[threadIdx.x >> 6] = v;
    __syncthreads();
    if (threadIdx.x == 0) {
        atomicAdd(out, partial[0] + partial[1] + partial[2] + partial[3]);
        __threadfence();
        unsigned old = atomicAdd(counter, 1u);
        if (old == (unsigned)(nblocks - 1)) {
            float tot = atomicAdd(out, 0.f);   // atomic read: all prior adds visible
            out[0] = sqrtf(tot);
        }
    }
}

// ---- Fallback path (small workspace): dense atomic SpMV ----
__global__ void spmv_fallback_kernel(const int* __restrict__ erow, const int* __restrict__ ecol,
                                     const float* __restrict__ ew, const float* __restrict__ s,
                                     float* __restrict__ t)
{
    int i = blockIdx.x * 256 + threadIdx.x;
    if (i >= NE / 4) return;
    int4   r4 = ((const int4*)erow)[i];
    int4   c4 = ((const int4*)ecol)[i];
    float4 w4 = ((const float4*)ew)[i];
    atomicAdd(&t[r4.x], w4.x * s[c4.x]);
    atomicAdd(&t[r4.y], w4.y * s[c4.y]);
    atomicAdd(&t[r4.z], w4.z * s[c4.z]);
    atomicAdd(&t[r4.w], w4.w * s[c4.w]);
}

__global__ void finish_fallback_kernel(const float* __restrict__ t, const float* __restrict__ b2,
                                       float* __restrict__ out)
{
    int n = blockIdx.x * 256 + threadIdx.x;
    float v = 0.f;
    if (n < NN) { float o = __sinf(t[n] + b2[0]); v = o * o; }
    #pragma unroll
    for (int off = 32; off; off >>= 1) v += __shfl_xor(v, off);
    __shared__ float partial[4];
    if ((threadIdx.x & 63) == 0) partial[threadIdx.x >> 6] = v;
    __syncthreads();
    if (threadIdx.x == 0)
        atomicAdd(out, partial[0] + partial[1] + partial[2] + partial[3]);
}

__global__ void sqrt_kernel(float* out) { out[0] = sqrtf(out[0]); }

__global__ void zero_kernel(float* t, float* out)
{
    int i = blockIdx.x * 256 + threadIdx.x;
    if (i < NN) t[i] = 0.f;
    if (i == 0) out[0] = 0.f;
}

extern "C" void kernel_launch(void* const* d_in, const int* in_sizes, int n_in,
                              void* d_out, int out_size, void* d_ws, size_t ws_size,
                              hipStream_t stream)
{
    const float* x   = (const float*)d_in[0];
    const float* W1  = (const float*)d_in[1];
    const float* b1  = (const float*)d_in[2];
    const float* W2  = (const float*)d_in[3];
    const float* b2  = (const float*)d_in[4];
    const int*   er  = (const int*)d_in[5];
    const int*   ec  = ((const int*)d_in[5]) + NE;
    const float* ew  = (const float*)d_in[6];
    float* out = (float*)d_out;

    float*    ws    = (float*)d_ws;
    float*    s_buf = ws + S_OFF;
    float*    P     = ws + P_OFF;
    unsigned* cnt   = (unsigned*)(ws + CNT_OFF);
    __bf16*   W1p   = (__bf16*)(ws + W1P_OFF);

    if (ws_size >= WS_NEED) {
        prep_w1_kernel<<<16, 256, 0, stream>>>(W1, W1p, out, cnt);
        stage1_kernel<<<NT, 256, 0, stream>>>(x, W1p, b1, W2, s_buf, out, cnt);
        spmv_lds_kernel<<<NR * EC, 1024, 0, stream>>>(er, ec, ew, s_buf, P);
        int fb = (NN + 255) / 256;
        finish_lds_kernel<<<fb, 256, 0, stream>>>(P, b2, out, cnt, fb);
    } else {
        // Dense-atomic fallback (needs ~700 KB of ws)
        __bf16*   W1pf = (__bf16*)(ws + 50176 + NN);
        unsigned* cntf = (unsigned*)(ws + 50176 + NN + DD * KD / 2);
        prep_w1_kernel<<<16, 256, 0, stream>>>(W1, W1pf, out, cntf);
        zero_kernel<<<(NN + 255) / 256, 256, 0, stream>>>(ws + 50176, out);
        stage1_kernel<<<NT, 256, 0, stream>>>(x, W1pf, b1, W2, s_buf, out, cntf);
        spmv_fallback_kernel<<<(NE / 4 + 255) / 256, 256, 0, stream>>>(er, ec, ew, s_buf, ws + 50176);
        finish_fallback_kernel<<<(NN + 255) / 256, 256, 0, stream>>>(ws + 50176, b2, out);
        sqrt_kernel<<<1, 1, 0, stream>>>(out);
    }
}